// Round 16
// baseline (165.787 us; speedup 1.0000x reference)
//
#include <hip/hip_runtime.h>
#include <hip/hip_fp16.h>
#include <float.h>

#define B 8
#define C 64
#define N 4096
#define O 64
#define KMAX 32
#define NREP 64   // stats replica buffers (atomic contention divider)

typedef unsigned short u16;
typedef unsigned int u32;
typedef unsigned long long u64;
typedef __attribute__((ext_vector_type(8))) u16 u16x8;
typedef __attribute__((ext_vector_type(8))) short bf16x8;
typedef __attribute__((ext_vector_type(4))) float f32x4;

__device__ __forceinline__ u16 f2bf(float f) {
    unsigned u = __builtin_bit_cast(unsigned, f);
    unsigned r = (u + 0x7FFFu + ((u >> 16) & 1)) >> 16;   // RTNE
    return (u16)r;
}

// ---------- fused prep: xt fp32, xtb bf16, xx, u/v fp16 ----------
__global__ __launch_bounds__(256) void ec_prep(const float* __restrict__ x,
                                               const float* __restrict__ W,
                                               float* __restrict__ xx,
                                               float* __restrict__ xt,
                                               u16* __restrict__ xtb,
                                               __half* __restrict__ u,
                                               __half* __restrict__ v) {
    __shared__ float xs[64][33];
    __shared__ __half2 Wp[C][65];
    __shared__ float rs[8][32];
    const int blk = blockIdx.x;            // B*N/32 = 1024
    const int b = blk >> 7;
    const int n0 = (blk & 127) << 5;
    const int t = threadIdx.x;
#pragma unroll
    for (int p = 0; p < 8; ++p) {
        int q = t + 256 * p; int c = q >> 5, j = q & 31;
        xs[c][j] = x[(size_t)b * C * N + (size_t)c * N + n0 + j];
    }
#pragma unroll
    for (int p = 0; p < 16; ++p) {
        int q = t + 256 * p; int o = q >> 6, c = q & 63;   // lanes: consecutive c
        float w1 = W[o * 128 + c];
        float w2 = W[o * 128 + 64 + c];
        Wp[c][o] = __floats2half2_rn(w1, w2 - w1);
    }
    __syncthreads();
    {
        const int j = t >> 3, g = t & 7;
        float vals[8]; float ss = 0.f;
#pragma unroll
        for (int i = 0; i < 8; ++i) { float f = xs[g * 8 + i][j]; vals[i] = f; ss += f * f; }
        rs[g][j] = ss;
        size_t rowb = ((size_t)b * N + n0 + j) * 64 + g * 8;
        float4 v0 = { vals[0], vals[1], vals[2], vals[3] };
        float4 v1 = { vals[4], vals[5], vals[6], vals[7] };
        *(float4*)&xt[rowb] = v0;
        *(float4*)&xt[rowb + 4] = v1;
        u16x8 h0;
#pragma unroll
        for (int i = 0; i < 8; ++i) h0[i] = f2bf(vals[i]);
        *(u16x8*)&xtb[rowb] = h0;
    }
    {
        const int o = t & 63, ji = t >> 6;
        float su[8] = {}, sv[8] = {};
#pragma unroll 1
        for (int c = 0; c < C; ++c) {
            __half2 wp = Wp[c][o];
            float w1 = __low2float(wp), wd = __high2float(wp);
#pragma unroll
            for (int p = 0; p < 8; ++p) {
                float xv = xs[c][ji + 4 * p];
                su[p] = fmaf(xv, w1, su[p]);
                sv[p] = fmaf(xv, wd, sv[p]);
            }
        }
#pragma unroll
        for (int p = 0; p < 8; ++p) {
            size_t base = ((size_t)b * N + n0 + ji + 4 * p) * O + o;
            u[base] = __float2half(su[p]);
            v[base] = __float2half(sv[p]);
        }
    }
    __syncthreads();
    if (t < 32) {
        float a = 0.f;
#pragma unroll
        for (int g = 0; g < 8; ++g) a += rs[g][t];
        xx[(size_t)b * N + n0 + t] = a;
    }
}

// ---------- in-register compare-exchange (descending: first arg keeps max) ----------
#define CXD(a, b) { u32 mx_ = max(a, b); b = min(a, b); a = mx_; }
// Batcher optimal 19-comparator sort-8 on array (constant indices), descending
#define BSORT8A(a) { \
    CXD(a[0],a[1]) CXD(a[2],a[3]) CXD(a[4],a[5]) CXD(a[6],a[7]) \
    CXD(a[0],a[2]) CXD(a[1],a[3]) CXD(a[4],a[6]) CXD(a[5],a[7]) \
    CXD(a[1],a[2]) CXD(a[5],a[6]) CXD(a[0],a[4]) CXD(a[3],a[7]) \
    CXD(a[1],a[5]) CXD(a[2],a[6]) \
    CXD(a[1],a[4]) CXD(a[3],a[6]) \
    CXD(a[2],a[4]) CXD(a[3],a[5]) \
    CXD(a[3],a[4]) }
// merge sorted-8 e into sorted-8 a keeping top-8 sorted (8 max + 12 CX clean)
#define MERGEA(a, e) { \
    a[0] = max(a[0], e[7]); a[1] = max(a[1], e[6]); \
    a[2] = max(a[2], e[5]); a[3] = max(a[3], e[4]); \
    a[4] = max(a[4], e[3]); a[5] = max(a[5], e[2]); \
    a[6] = max(a[6], e[1]); a[7] = max(a[7], e[0]); \
    CXD(a[0],a[4]) CXD(a[1],a[5]) CXD(a[2],a[6]) CXD(a[3],a[7]) \
    CXD(a[0],a[2]) CXD(a[1],a[3]) CXD(a[4],a[6]) CXD(a[5],a[7]) \
    CXD(a[0],a[1]) CXD(a[2],a[3]) CXD(a[4],a[5]) CXD(a[6],a[7]) }

// ---------- MFMA distance + fused per-(row,128-col-chunk) top-8 ----------
// Key: dvp = 2*acc - xm + 2560 in (2230,2780) -> single binade [2048,4096)
// -> (u16)(bits>>7) is monotone in d, granularity 2^-5.
// cand[((b*N+row)*32 + chunk)*8 + s] : packed u32 = (key16<<12)|(4095-m)
__global__ __launch_bounds__(256) void ec_gemm(const u16* __restrict__ xtb,
                                               const float* __restrict__ xx,
                                               u32* __restrict__ cand) {
    __shared__ u16 lds[18432 + 8];
    const int t = threadIdx.x;
    const int m0 = blockIdx.x * 128, n0 = blockIdx.y * 128;
    const int b = blockIdx.z;
    const u16* xa = xtb + (size_t)b * N * 64;
#pragma unroll
    for (int p = 0; p < 4; ++p) {
        int q = t + 256 * p;
        int row = q >> 3, ch = q & 7;
        int by = (row * 128 + ch * 16) ^ ((row & 7) << 4);
        *(u16x8*)((char*)lds + by) = *(const u16x8*)&xa[(size_t)(n0 + row) * 64 + ch * 8];
        *(u16x8*)((char*)lds + 16384 + by) = *(const u16x8*)&xa[(size_t)(m0 + row) * 64 + ch * 8];
    }
    __syncthreads();
    const int w = t >> 6, lane = t & 63;
    const int wr = w >> 1, wc = w & 1;
    const int fr = lane & 15, fg = lane >> 4;
    f32x4 acc[4][4] = {};
#pragma unroll
    for (int ks = 0; ks < 2; ++ks) {
        bf16x8 af[4], bg[4];
#pragma unroll
        for (int fi = 0; fi < 4; ++fi) {
            int rowA = 64 * wr + 16 * fi + fr;
            int byA = (rowA * 128 + ks * 64 + fg * 16) ^ ((rowA & 7) << 4);
            af[fi] = *(const bf16x8*)((const char*)lds + byA);
            int rowB = 64 * wc + 16 * fi + fr;
            int byB = (rowB * 128 + ks * 64 + fg * 16) ^ ((rowB & 7) << 4);
            bg[fi] = *(const bf16x8*)((const char*)lds + 16384 + byB);
        }
#pragma unroll
        for (int fi = 0; fi < 4; ++fi)
#pragma unroll
            for (int fj = 0; fj < 4; ++fj)
                acc[fi][fj] = __builtin_amdgcn_mfma_f32_16x16x32_bf16(af[fi], bg[fj], acc[fi][fj], 0, 0, 0);
    }
    float xmK[4];
#pragma unroll
    for (int fj = 0; fj < 4; ++fj)
        xmK[fj] = 2560.f - xx[(size_t)b * N + m0 + 64 * wc + 16 * fj + fr];
    __syncthreads();                        // staging LDS dead; reuse for epilogue
    u16* ep = lds + w * 4608;               // 64 rows x stride 72 u16 (144 B)
#pragma unroll
    for (int fi = 0; fi < 4; ++fi)
#pragma unroll
        for (int fj = 0; fj < 4; ++fj)
#pragma unroll
            for (int r = 0; r < 4; ++r) {
                float dvp = fmaf(2.f, acc[fi][fj][r], xmK[fj]);   // in (2230,2780)
                u32 bits = __builtin_bit_cast(u32, dvp);
                int row = 16 * fi + fg * 4 + r, col = 16 * fj + fr;
                ep[row * 72 + col] = (u16)(bits >> 7);            // monotone key
            }
    __syncthreads();
    // per-lane: row = lane; tree-merged sorting-network top-8 over own 64 cols
    const u16* myrow = lds + w * 4608 + lane * 72;
    const int mbase = m0 + (wc << 6);
    const u32 invb = (u32)(4095 - mbase);   // wave-uniform
    u32 g[8][8];
#pragma unroll
    for (int gg = 0; gg < 8; ++gg) {
        u16x8 q = *(const u16x8*)&myrow[gg * 8];
        const u32 ig = invb - (u32)(gg * 8);
#pragma unroll
        for (int jj = 0; jj < 8; ++jj)
            g[gg][jj] = ((u32)q[jj] << 12) | (ig - (u32)jj);
        BSORT8A(g[gg])
    }
    // merge tree: depth 3, same-level merges independent
    MERGEA(g[0], g[1]) MERGEA(g[2], g[3]) MERGEA(g[4], g[5]) MERGEA(g[6], g[7])
    MERGEA(g[0], g[2]) MERGEA(g[4], g[6])
    MERGEA(g[0], g[4])
    // cross-warp merge: wc=1 half into wc=0 half -> top-8 per 128-col chunk
    __syncthreads();                        // all myrow reads done
    u32* mbuf = (u32*)lds;                  // 4 KB reuse
    if (wc) {
        u32* mp = mbuf + (size_t)((wr << 6) | lane) * 8;
        uint4 w0 = { g[0][0], g[0][1], g[0][2], g[0][3] };
        uint4 w1 = { g[0][4], g[0][5], g[0][6], g[0][7] };
        *(uint4*)mp = w0;
        *(uint4*)(mp + 4) = w1;
    }
    __syncthreads();
    if (!wc) {
        const u32* mp = mbuf + (size_t)((wr << 6) | lane) * 8;
        uint4 b0 = *(const uint4*)mp, b1 = *(const uint4*)(mp + 4);
        u32 e[8] = { b0.x, b0.y, b0.z, b0.w, b1.x, b1.y, b1.z, b1.w };
        MERGEA(g[0], e)
        const int row_g = n0 + 64 * wr + lane;
        u32* cp = cand + (((size_t)b * N + row_g) * 32 + blockIdx.x) * 8;
        uint4 w0 = { g[0][0], g[0][1], g[0][2], g[0][3] };
        uint4 w1 = { g[0][4], g[0][5], g[0][6], g[0][7] };
        *(uint4*)cp = w0;
        *(uint4*)(cp + 4) = w1;
    }
}

// ---------- distributed merge-tree helpers (4 keys/lane) ----------
#define CX4(i, j) { u32 mn_ = min(c[i], c[j]); c[i] = max(c[i], c[j]); c[j] = mn_; }
#define CLEAN4IN() { CX4(0,2) CX4(1,3) CX4(0,1) CX4(2,3) }
#define DSTEP(xorm, bit) { \
    u32 pr_[4]; \
    _Pragma("unroll") for (int i_ = 0; i_ < 4; ++i_) pr_[i_] = __shfl_xor(c[i_], xorm); \
    bool km_ = (lane & (bit)) == 0; \
    _Pragma("unroll") for (int i_ = 0; i_ < 4; ++i_) \
        c[i_] = km_ ? max(c[i_], pr_[i_]) : min(c[i_], pr_[i_]); }

// ---------- sel: merge-tree top-32 -> exact rescore -> sort-32 -> stats ----------
__global__ __launch_bounds__(256) void ec_sel(const u32* __restrict__ cand,
                                              const float* __restrict__ xt,
                                              const float* __restrict__ xx,
                                              const __half* __restrict__ u,
                                              const __half* __restrict__ v,
                                              const int* __restrict__ kptr,
                                              __half2* __restrict__ ext,
                                              float* __restrict__ statsR) {
    __shared__ float sxn[4][64];
    __shared__ int scand[4][32];
    __shared__ float rsum[256], rsum2[256];
    const int t = threadIdx.x, w = t >> 6, lane = t & 63;
    const int b = blockIdx.y;
    const int n = blockIdx.x * 4 + w;
    const int k = *kptr;

    // lane pair (2c,2c+1) holds chunk c's sorted-8; rank = 4*(lane&1)+reg
    const u32* cp = cand + (((size_t)b * N + n) * 32 + (lane >> 1)) * 8 + (lane & 1) * 4;
    uint4 a0 = *(const uint4*)cp;
    u32 c[4] = { a0.x, a0.y, a0.z, a0.w };

    // L1 (xor2): chunk pairs -> sorted-16 over 4 lanes
    {
        u32 pr[4];
#pragma unroll
        for (int i = 0; i < 4; ++i) pr[i] = __shfl_xor(c[3 - i], 3);
        bool lo = (lane & 2) == 0;
#pragma unroll
        for (int i = 0; i < 4; ++i) {
            u32 mx = max(c[i], pr[i]), mn = min(c[i], pr[i]);
            c[i] = lo ? mx : mn;
        }
        DSTEP(1, 1)
        CLEAN4IN()
    }
    // L2 (xor4): -> sorted-32 over 8 lanes
    {
        u32 pr[4];
#pragma unroll
        for (int i = 0; i < 4; ++i) pr[i] = __shfl_xor(c[3 - i], 7);
        bool lo = (lane & 4) == 0;
#pragma unroll
        for (int i = 0; i < 4; ++i) {
            u32 mx = max(c[i], pr[i]), mn = min(c[i], pr[i]);
            c[i] = lo ? mx : mn;
        }
        DSTEP(2, 2) DSTEP(1, 1)
        CLEAN4IN()
    }
    // L3-5: top-32 halver + bitonic-32 clean (8-lane groups 8/16/32 apart)
#define MT32(mask) { \
        u32 pr_[4]; \
        _Pragma("unroll") for (int i_ = 0; i_ < 4; ++i_) pr_[i_] = __shfl_xor(c[3 - i_], mask); \
        _Pragma("unroll") for (int i_ = 0; i_ < 4; ++i_) c[i_] = max(c[i_], pr_[i_]); \
        DSTEP(4, 4) DSTEP(2, 2) DSTEP(1, 1) CLEAN4IN() }
    MT32(15)
    MT32(23)
    MT32(39)
#undef MT32

    // lanes 0-7 hold global top-32 sorted desc: rank = 4*lane + reg
    if (lane < 8) {
#pragma unroll
        for (int i = 0; i < 4; ++i) scand[w][lane * 4 + i] = 4095 - (int)(c[i] & 0xFFFu);
    }
    sxn[w][lane] = xt[((size_t)b * N + n) * 64 + lane];
    __syncthreads();

    // exact fp32 rescore: lane = (candidate jc, c-half h)
    const float* xt_ = xt + (size_t)b * N * 64;
    const int jc = lane & 31, h = lane >> 5;
    const int mj = scand[w][jc];
    const float* xr = xt_ + (size_t)mj * 64 + h * 32;
    float acc = 0.f;
#pragma unroll
    for (int q8 = 0; q8 < 8; ++q8) {
        float4 g4 = *(const float4*)&xr[q8 * 4];
        float4 xn4 = *(const float4*)&sxn[w][h * 32 + q8 * 4];
        acc += g4.x * xn4.x + g4.y * xn4.y + g4.z * xn4.z + g4.w * xn4.w;
    }
    acc += __shfl_xor(acc, 32);
    float ex = 2.f * acc - xx[(size_t)b * N + mj];
    unsigned fu = __builtin_bit_cast(unsigned, ex);
    unsigned sf = fu ^ (unsigned)(((int)fu >> 31) | 0x80000000);
    u64 key = ((u64)sf << 12) | (u64)(4095 - mj);
    if (h) key = 0;                        // duplicate copy lives in lanes 32..63

    // descending bitonic sort of 32 u64 keys (lanes 0..31; halves isolated)
#pragma unroll
    for (int ls = 1; ls <= 5; ++ls) {
        const int s = 1 << ls;
        const bool lb = (lane & s) == 0;
#pragma unroll
        for (int dd = s >> 1; dd >= 1; dd >>= 1) {
            const bool km = ((lane & dd) == 0) == lb;
            u64 pv = __shfl_xor(key, dd);
            u64 mn = key < pv ? key : pv;
            u64 mx = key < pv ? pv : key;
            key = km ? mx : mn;
        }
    }
    int m_final = 4095 - (int)(key & 0xFFFu);   // lane r (<32) = r-th best exact

    // publish exact-sorted indices for vectorized broadcast gather
    if (lane < KMAX) scand[w][lane] = m_final;

    // fused BN stats gather: lane = o
    const __half* ub = u + (size_t)b * N * O;
    size_t rowb = (size_t)b * N + n;
    float vv = __half2float(v[rowb * O + lane]);
    float gmax = -FLT_MAX, gmin = FLT_MAX, gs = 0.f, gs2 = 0.f;
    if (k == 20) {
        const int4* ip = (const int4*)&scand[w][0];
        int4 q0 = ip[0], q1 = ip[1], q2 = ip[2], q3 = ip[3], q4 = ip[4];
        float g[20];
        g[0]  = __half2float(ub[(size_t)q0.x * O + lane]);
        g[1]  = __half2float(ub[(size_t)q0.y * O + lane]);
        g[2]  = __half2float(ub[(size_t)q0.z * O + lane]);
        g[3]  = __half2float(ub[(size_t)q0.w * O + lane]);
        g[4]  = __half2float(ub[(size_t)q1.x * O + lane]);
        g[5]  = __half2float(ub[(size_t)q1.y * O + lane]);
        g[6]  = __half2float(ub[(size_t)q1.z * O + lane]);
        g[7]  = __half2float(ub[(size_t)q1.w * O + lane]);
        g[8]  = __half2float(ub[(size_t)q2.x * O + lane]);
        g[9]  = __half2float(ub[(size_t)q2.y * O + lane]);
        g[10] = __half2float(ub[(size_t)q2.z * O + lane]);
        g[11] = __half2float(ub[(size_t)q2.w * O + lane]);
        g[12] = __half2float(ub[(size_t)q3.x * O + lane]);
        g[13] = __half2float(ub[(size_t)q3.y * O + lane]);
        g[14] = __half2float(ub[(size_t)q3.z * O + lane]);
        g[15] = __half2float(ub[(size_t)q3.w * O + lane]);
        g[16] = __half2float(ub[(size_t)q4.x * O + lane]);
        g[17] = __half2float(ub[(size_t)q4.y * O + lane]);
        g[18] = __half2float(ub[(size_t)q4.z * O + lane]);
        g[19] = __half2float(ub[(size_t)q4.w * O + lane]);
#pragma unroll
        for (int kk = 0; kk < 20; ++kk) {
            gs += g[kk]; gs2 += g[kk] * g[kk];
            gmax = fmaxf(gmax, g[kk]); gmin = fminf(gmin, g[kk]);
        }
    } else {
        int mks[KMAX];
#pragma unroll
        for (int kk = 0; kk < KMAX; ++kk) mks[kk] = __shfl(m_final, kk);
        float g[KMAX];
#pragma unroll
        for (int kk = 0; kk < KMAX; ++kk)
            g[kk] = __half2float(ub[(size_t)mks[kk] * O + lane]);
#pragma unroll
        for (int kk = 0; kk < KMAX; ++kk) {
            if (kk < k) {
                gs += g[kk]; gs2 += g[kk] * g[kk];
                gmax = fmaxf(gmax, g[kk]); gmin = fminf(gmin, g[kk]);
            }
        }
    }
    float fk = (float)k;
    float s  = gs + fk * vv;
    float s2 = gs2 + 2.f * vv * gs + fk * vv * vv;
    ext[rowb * O + lane] = __halves2half2(__float2half(gmax + vv), __float2half(gmin + vv));
    rsum[t] = s; rsum2[t] = s2;
    __syncthreads();
    if (t < 64) {
        float a  = rsum[t] + rsum[t + 64] + rsum[t + 128] + rsum[t + 192];
        float a2 = rsum2[t] + rsum2[t + 64] + rsum2[t + 128] + rsum2[t + 192];
        float* sr = statsR + (size_t)(blockIdx.x & (NREP - 1)) * 128;
        atomicAdd(&sr[t], a);
        atomicAdd(&sr[64 + t], a2);
    }
}

// ---------- output: replica-reduce BN affine + pick extreme + leaky + transpose ----------
__global__ __launch_bounds__(256) void ec_out(const __half2* __restrict__ ext,
                                              const float* __restrict__ statsR,
                                              const float* __restrict__ gamma,
                                              const float* __restrict__ beta,
                                              const int* __restrict__ kptr,
                                              float* __restrict__ out) {
    __shared__ float res[64][65];
    __shared__ float scs[64], shs[64];
    const int blk = blockIdx.x;            // B*N/64
    const int b = blk >> 6;
    const int n0 = (blk & 63) << 6;
    const int t = threadIdx.x;
    if (t < 64) {
        float s = 0.f, s2 = 0.f;
#pragma unroll 8
        for (int r = 0; r < NREP; ++r) {
            s  += statsR[r * 128 + t];
            s2 += statsR[r * 128 + 64 + t];
        }
        int k = *kptr;
        float M = (float)B * (float)N * (float)k;
        float mean = s / M;
        float var = fmaxf(s2 / M - mean * mean, 0.f);
        float sc = gamma[t] * rsqrtf(var + 1e-5f);
        scs[t] = sc;
        shs[t] = beta[t] - mean * sc;
    }
    __syncthreads();
    {
        const int o = t & 63, ni = t >> 6;
        float sc = scs[o], sh = shs[o];
#pragma unroll 1
        for (int p = 0; p < 16; ++p) {
            int nl = ni * 16 + p;
            size_t a = ((size_t)b * N + n0 + nl) * O + o;
            __half2 e = ext[a];
            float y = (sc >= 0.f) ? __low2float(e) : __high2float(e);
            float z = sc * y + sh;
            res[nl][o] = (z >= 0.f) ? z : 0.2f * z;
        }
    }
    __syncthreads();
    {
        const int j = t & 63, oi = t >> 6;
#pragma unroll 1
        for (int p = 0; p < 16; ++p) {
            int o2 = oi * 16 + p;
            out[(size_t)b * O * N + (size_t)o2 * N + n0 + j] = res[j][o2];
        }
    }
}

extern "C" void kernel_launch(void* const* d_in, const int* in_sizes, int n_in,
                              void* d_out, int out_size, void* d_ws, size_t ws_size,
                              hipStream_t stream) {
    const float* x     = (const float*)d_in[0];
    const float* W     = (const float*)d_in[1];
    const float* gamma = (const float*)d_in[2];
    const float* beta  = (const float*)d_in[3];
    const int*   kptr  = (const int*)d_in[4];
    float* out = (float*)d_out;

    char* ws = (char*)d_ws;
    u32*    cand = (u32*)ws;    ws += (size_t)B * N * 32 * 8 * 4;  // 32 MB
    float*  xx   = (float*)ws;  ws += (size_t)B * N * 4;
    float*  xt   = (float*)ws;  ws += (size_t)B * N * C * 4;       // 8 MB
    u16*    xtb  = (u16*)ws;    ws += (size_t)B * N * C * 2;       // 4 MB
    __half* u_t  = (__half*)ws; ws += (size_t)B * N * O * 2;       // 4 MB
    __half* v_t  = (__half*)ws; ws += (size_t)B * N * O * 2;       // 4 MB
    __half2* ext = (__half2*)ws; ws += (size_t)B * N * O * 4;      // 8 MB
    float* statsR = (float*)ws; ws += (size_t)NREP * 128 * 4;      // 32 KB
    (void)ws;

    hipMemsetAsync(statsR, 0, NREP * 128 * 4, stream);
    ec_prep<<<B * N / 32, 256, 0, stream>>>(x, W, xx, xt, xtb, u_t, v_t);
    ec_gemm<<<dim3(N / 128, N / 128, B), 256, 0, stream>>>(xtb, xx, cand);
    ec_sel<<<dim3(N / 4, B), 256, 0, stream>>>(cand, xt, xx, u_t, v_t, kptr, ext, statsR);
    ec_out<<<B * N / 64, 256, 0, stream>>>(ext, statsR, gamma, beta, kptr, out);
}

// Round 17
// 151.251 us; speedup vs baseline: 1.0961x; 1.0961x over previous
//
#include <hip/hip_runtime.h>
#include <hip/hip_fp16.h>
#include <float.h>

#define B 8
#define C 64
#define N 4096
#define O 64
#define KMAX 32
#define NREP 64   // stats replica buffers (atomic contention divider)

typedef unsigned short u16;
typedef unsigned int u32;
typedef unsigned long long u64;
typedef __attribute__((ext_vector_type(8))) u16 u16x8;
typedef __attribute__((ext_vector_type(8))) short bf16x8;
typedef __attribute__((ext_vector_type(4))) float f32x4;

__device__ __forceinline__ u16 f2bf(float f) {
    unsigned u = __builtin_bit_cast(unsigned, f);
    unsigned r = (u + 0x7FFFu + ((u >> 16) & 1)) >> 16;   // RTNE
    return (u16)r;
}

// ---------- fused prep: xt fp32, xtb bf16, xx, u/v fp16 ----------
__global__ __launch_bounds__(256) void ec_prep(const float* __restrict__ x,
                                               const float* __restrict__ W,
                                               float* __restrict__ xx,
                                               float* __restrict__ xt,
                                               u16* __restrict__ xtb,
                                               __half* __restrict__ u,
                                               __half* __restrict__ v) {
    __shared__ float xs[64][33];
    __shared__ __half2 Wp[C][65];
    __shared__ float rs[8][32];
    const int blk = blockIdx.x;            // B*N/32 = 1024
    const int b = blk >> 7;
    const int n0 = (blk & 127) << 5;
    const int t = threadIdx.x;
#pragma unroll
    for (int p = 0; p < 8; ++p) {
        int q = t + 256 * p; int c = q >> 5, j = q & 31;
        xs[c][j] = x[(size_t)b * C * N + (size_t)c * N + n0 + j];
    }
#pragma unroll
    for (int p = 0; p < 16; ++p) {
        int q = t + 256 * p; int o = q >> 6, c = q & 63;   // lanes: consecutive c
        float w1 = W[o * 128 + c];
        float w2 = W[o * 128 + 64 + c];
        Wp[c][o] = __floats2half2_rn(w1, w2 - w1);
    }
    __syncthreads();
    {
        const int j = t >> 3, g = t & 7;
        float vals[8]; float ss = 0.f;
#pragma unroll
        for (int i = 0; i < 8; ++i) { float f = xs[g * 8 + i][j]; vals[i] = f; ss += f * f; }
        rs[g][j] = ss;
        size_t rowb = ((size_t)b * N + n0 + j) * 64 + g * 8;
        float4 v0 = { vals[0], vals[1], vals[2], vals[3] };
        float4 v1 = { vals[4], vals[5], vals[6], vals[7] };
        *(float4*)&xt[rowb] = v0;
        *(float4*)&xt[rowb + 4] = v1;
        u16x8 h0;
#pragma unroll
        for (int i = 0; i < 8; ++i) h0[i] = f2bf(vals[i]);
        *(u16x8*)&xtb[rowb] = h0;
    }
    {
        const int o = t & 63, ji = t >> 6;
        float su[8] = {}, sv[8] = {};
#pragma unroll 1
        for (int c = 0; c < C; ++c) {
            __half2 wp = Wp[c][o];
            float w1 = __low2float(wp), wd = __high2float(wp);
#pragma unroll
            for (int p = 0; p < 8; ++p) {
                float xv = xs[c][ji + 4 * p];
                su[p] = fmaf(xv, w1, su[p]);
                sv[p] = fmaf(xv, wd, sv[p]);
            }
        }
#pragma unroll
        for (int p = 0; p < 8; ++p) {
            size_t base = ((size_t)b * N + n0 + ji + 4 * p) * O + o;
            u[base] = __float2half(su[p]);
            v[base] = __float2half(sv[p]);
        }
    }
    __syncthreads();
    if (t < 32) {
        float a = 0.f;
#pragma unroll
        for (int g = 0; g < 8; ++g) a += rs[g][t];
        xx[(size_t)b * N + n0 + t] = a;
    }
}

// ---------- in-register compare-exchange (descending: first arg keeps max) ----------
#define CXD(a, b) { u32 mx_ = max(a, b); b = min(a, b); a = mx_; }
// Batcher optimal 19-comparator sort-8 on array (constant indices), descending
#define BSORT8A(a) { \
    CXD(a[0],a[1]) CXD(a[2],a[3]) CXD(a[4],a[5]) CXD(a[6],a[7]) \
    CXD(a[0],a[2]) CXD(a[1],a[3]) CXD(a[4],a[6]) CXD(a[5],a[7]) \
    CXD(a[1],a[2]) CXD(a[5],a[6]) CXD(a[0],a[4]) CXD(a[3],a[7]) \
    CXD(a[1],a[5]) CXD(a[2],a[6]) \
    CXD(a[1],a[4]) CXD(a[3],a[6]) \
    CXD(a[2],a[4]) CXD(a[3],a[5]) \
    CXD(a[3],a[4]) }
// merge sorted-8 e into sorted-8 a keeping top-8 sorted (8 max + 12 CX clean)
#define MERGEA(a, e) { \
    a[0] = max(a[0], e[7]); a[1] = max(a[1], e[6]); \
    a[2] = max(a[2], e[5]); a[3] = max(a[3], e[4]); \
    a[4] = max(a[4], e[3]); a[5] = max(a[5], e[2]); \
    a[6] = max(a[6], e[1]); a[7] = max(a[7], e[0]); \
    CXD(a[0],a[4]) CXD(a[1],a[5]) CXD(a[2],a[6]) CXD(a[3],a[7]) \
    CXD(a[0],a[2]) CXD(a[1],a[3]) CXD(a[4],a[6]) CXD(a[5],a[7]) \
    CXD(a[0],a[1]) CXD(a[2],a[3]) CXD(a[4],a[5]) CXD(a[6],a[7]) }

// ---------- MFMA distance + fused per-(row,128-col-chunk) top-8 ----------
// Key: dvp = 2*acc - xm + 2560 in (2230,2780) -> single binade [2048,4096)
// -> (u16)(bits>>7) is monotone in d, granularity 2^-5.
// cand[((b*N+row)*32 + chunk)*8 + s] : packed u32 = (key16<<12)|(4095-m)
__global__ __launch_bounds__(256) void ec_gemm(const u16* __restrict__ xtb,
                                               const float* __restrict__ xx,
                                               u32* __restrict__ cand) {
    __shared__ u16 lds[18432 + 8];
    const int t = threadIdx.x;
    const int m0 = blockIdx.x * 128, n0 = blockIdx.y * 128;
    const int b = blockIdx.z;
    const u16* xa = xtb + (size_t)b * N * 64;
#pragma unroll
    for (int p = 0; p < 4; ++p) {
        int q = t + 256 * p;
        int row = q >> 3, ch = q & 7;
        int by = (row * 128 + ch * 16) ^ ((row & 7) << 4);
        *(u16x8*)((char*)lds + by) = *(const u16x8*)&xa[(size_t)(n0 + row) * 64 + ch * 8];
        *(u16x8*)((char*)lds + 16384 + by) = *(const u16x8*)&xa[(size_t)(m0 + row) * 64 + ch * 8];
    }
    __syncthreads();
    const int w = t >> 6, lane = t & 63;
    const int wr = w >> 1, wc = w & 1;
    const int fr = lane & 15, fg = lane >> 4;
    f32x4 acc[4][4] = {};
#pragma unroll
    for (int ks = 0; ks < 2; ++ks) {
        bf16x8 af[4], bg[4];
#pragma unroll
        for (int fi = 0; fi < 4; ++fi) {
            int rowA = 64 * wr + 16 * fi + fr;
            int byA = (rowA * 128 + ks * 64 + fg * 16) ^ ((rowA & 7) << 4);
            af[fi] = *(const bf16x8*)((const char*)lds + byA);
            int rowB = 64 * wc + 16 * fi + fr;
            int byB = (rowB * 128 + ks * 64 + fg * 16) ^ ((rowB & 7) << 4);
            bg[fi] = *(const bf16x8*)((const char*)lds + 16384 + byB);
        }
#pragma unroll
        for (int fi = 0; fi < 4; ++fi)
#pragma unroll
            for (int fj = 0; fj < 4; ++fj)
                acc[fi][fj] = __builtin_amdgcn_mfma_f32_16x16x32_bf16(af[fi], bg[fj], acc[fi][fj], 0, 0, 0);
    }
    float xmK[4];
#pragma unroll
    for (int fj = 0; fj < 4; ++fj)
        xmK[fj] = 2560.f - xx[(size_t)b * N + m0 + 64 * wc + 16 * fj + fr];
    __syncthreads();                        // staging LDS dead; reuse for epilogue
    u16* ep = lds + w * 4608;               // 64 rows x stride 72 u16 (144 B)
#pragma unroll
    for (int fi = 0; fi < 4; ++fi)
#pragma unroll
        for (int fj = 0; fj < 4; ++fj)
#pragma unroll
            for (int r = 0; r < 4; ++r) {
                float dvp = fmaf(2.f, acc[fi][fj][r], xmK[fj]);   // in (2230,2780)
                u32 bits = __builtin_bit_cast(u32, dvp);
                int row = 16 * fi + fg * 4 + r, col = 16 * fj + fr;
                ep[row * 72 + col] = (u16)(bits >> 7);            // monotone key
            }
    __syncthreads();
    // per-lane: row = lane; 2-stream interleaved sorting-network top-8 over 64 cols
    const u16* myrow = lds + w * 4608 + lane * 72;
    const int mbase = m0 + (wc << 6);
    const u32 invb = (u32)(4095 - mbase);   // wave-uniform
    u32 tA[8], tB[8];
#define LOADG(dst, gg) { \
        u16x8 q = *(const u16x8*)&myrow[(gg) * 8]; \
        const u32 ig = invb - (u32)((gg) * 8); \
        _Pragma("unroll") for (int jj = 0; jj < 8; ++jj) \
            dst[jj] = ((u32)q[jj] << 12) | (ig - (u32)jj); \
        BSORT8A(dst) }
    LOADG(tA, 0)
    LOADG(tB, 4)
#pragma unroll
    for (int gg = 1; gg < 4; ++gg) {
        u32 eA[8], eB[8];
        LOADG(eA, gg)
        LOADG(eB, gg + 4)
        MERGEA(tA, eA)
        MERGEA(tB, eB)
    }
    MERGEA(tA, tB)
#undef LOADG
    // cross-warp merge: wc=1 half into wc=0 half -> top-8 per 128-col chunk
    __syncthreads();                        // all myrow reads done
    u32* mbuf = (u32*)lds;                  // 4 KB reuse
    if (wc) {
        u32* mp = mbuf + (size_t)((wr << 6) | lane) * 8;
        uint4 w0 = { tA[0], tA[1], tA[2], tA[3] };
        uint4 w1 = { tA[4], tA[5], tA[6], tA[7] };
        *(uint4*)mp = w0;
        *(uint4*)(mp + 4) = w1;
    }
    __syncthreads();
    if (!wc) {
        const u32* mp = mbuf + (size_t)((wr << 6) | lane) * 8;
        uint4 b0 = *(const uint4*)mp, b1 = *(const uint4*)(mp + 4);
        u32 e[8] = { b0.x, b0.y, b0.z, b0.w, b1.x, b1.y, b1.z, b1.w };
        MERGEA(tA, e)
        const int row_g = n0 + 64 * wr + lane;
        u32* cp = cand + (((size_t)b * N + row_g) * 32 + blockIdx.x) * 8;
        uint4 w0 = { tA[0], tA[1], tA[2], tA[3] };
        uint4 w1 = { tA[4], tA[5], tA[6], tA[7] };
        *(uint4*)cp = w0;
        *(uint4*)(cp + 4) = w1;
    }
}

// ---------- distributed merge-tree helpers (4 keys/lane) ----------
#define CX4(i, j) { u32 mn_ = min(c[i], c[j]); c[i] = max(c[i], c[j]); c[j] = mn_; }
#define CLEAN4IN() { CX4(0,2) CX4(1,3) CX4(0,1) CX4(2,3) }
#define DSTEP(xorm, bit) { \
    u32 pr_[4]; \
    _Pragma("unroll") for (int i_ = 0; i_ < 4; ++i_) pr_[i_] = __shfl_xor(c[i_], xorm); \
    bool km_ = (lane & (bit)) == 0; \
    _Pragma("unroll") for (int i_ = 0; i_ < 4; ++i_) \
        c[i_] = km_ ? max(c[i_], pr_[i_]) : min(c[i_], pr_[i_]); }

// ---------- sel: merge-tree top-32 -> exact rescore -> sort-32 -> stats ----------
__global__ __launch_bounds__(256) void ec_sel(const u32* __restrict__ cand,
                                              const float* __restrict__ xt,
                                              const float* __restrict__ xx,
                                              const __half* __restrict__ u,
                                              const __half* __restrict__ v,
                                              const int* __restrict__ kptr,
                                              __half2* __restrict__ ext,
                                              float* __restrict__ statsR) {
    __shared__ float sxn[4][64];
    __shared__ int scand[4][32];
    __shared__ float rsum[256], rsum2[256];
    const int t = threadIdx.x, w = t >> 6, lane = t & 63;
    const int b = blockIdx.y;
    const int n = blockIdx.x * 4 + w;
    const int k = *kptr;

    // lane pair (2c,2c+1) holds chunk c's sorted-8; rank = 4*(lane&1)+reg
    const u32* cp = cand + (((size_t)b * N + n) * 32 + (lane >> 1)) * 8 + (lane & 1) * 4;
    uint4 a0 = *(const uint4*)cp;
    u32 c[4] = { a0.x, a0.y, a0.z, a0.w };

    // L1 (xor2): chunk pairs -> sorted-16 over 4 lanes
    {
        u32 pr[4];
#pragma unroll
        for (int i = 0; i < 4; ++i) pr[i] = __shfl_xor(c[3 - i], 3);
        bool lo = (lane & 2) == 0;
#pragma unroll
        for (int i = 0; i < 4; ++i) {
            u32 mx = max(c[i], pr[i]), mn = min(c[i], pr[i]);
            c[i] = lo ? mx : mn;
        }
        DSTEP(1, 1)
        CLEAN4IN()
    }
    // L2 (xor4): -> sorted-32 over 8 lanes
    {
        u32 pr[4];
#pragma unroll
        for (int i = 0; i < 4; ++i) pr[i] = __shfl_xor(c[3 - i], 7);
        bool lo = (lane & 4) == 0;
#pragma unroll
        for (int i = 0; i < 4; ++i) {
            u32 mx = max(c[i], pr[i]), mn = min(c[i], pr[i]);
            c[i] = lo ? mx : mn;
        }
        DSTEP(2, 2) DSTEP(1, 1)
        CLEAN4IN()
    }
    // L3-5: top-32 halver + bitonic-32 clean (8-lane groups 8/16/32 apart)
#define MT32(mask) { \
        u32 pr_[4]; \
        _Pragma("unroll") for (int i_ = 0; i_ < 4; ++i_) pr_[i_] = __shfl_xor(c[3 - i_], mask); \
        _Pragma("unroll") for (int i_ = 0; i_ < 4; ++i_) c[i_] = max(c[i_], pr_[i_]); \
        DSTEP(4, 4) DSTEP(2, 2) DSTEP(1, 1) CLEAN4IN() }
    MT32(15)
    MT32(23)
    MT32(39)
#undef MT32

    // lanes 0-7 hold global top-32 sorted desc: rank = 4*lane + reg
    if (lane < 8) {
#pragma unroll
        for (int i = 0; i < 4; ++i) scand[w][lane * 4 + i] = 4095 - (int)(c[i] & 0xFFFu);
    }
    sxn[w][lane] = xt[((size_t)b * N + n) * 64 + lane];
    __syncthreads();

    // exact fp32 rescore: lane = (candidate jc, c-half h)
    const float* xt_ = xt + (size_t)b * N * 64;
    const int jc = lane & 31, h = lane >> 5;
    const int mj = scand[w][jc];
    const float* xr = xt_ + (size_t)mj * 64 + h * 32;
    float acc = 0.f;
#pragma unroll
    for (int q8 = 0; q8 < 8; ++q8) {
        float4 g4 = *(const float4*)&xr[q8 * 4];
        float4 xn4 = *(const float4*)&sxn[w][h * 32 + q8 * 4];
        acc += g4.x * xn4.x + g4.y * xn4.y + g4.z * xn4.z + g4.w * xn4.w;
    }
    acc += __shfl_xor(acc, 32);
    float ex = 2.f * acc - xx[(size_t)b * N + mj];
    unsigned fu = __builtin_bit_cast(unsigned, ex);
    unsigned sf = fu ^ (unsigned)(((int)fu >> 31) | 0x80000000);
    u64 key = ((u64)sf << 12) | (u64)(4095 - mj);
    if (h) key = 0;                        // duplicate copy lives in lanes 32..63

    // descending bitonic sort of 32 u64 keys (lanes 0..31; halves isolated)
#pragma unroll
    for (int ls = 1; ls <= 5; ++ls) {
        const int s = 1 << ls;
        const bool lb = (lane & s) == 0;
#pragma unroll
        for (int dd = s >> 1; dd >= 1; dd >>= 1) {
            const bool km = ((lane & dd) == 0) == lb;
            u64 pv = __shfl_xor(key, dd);
            u64 mn = key < pv ? key : pv;
            u64 mx = key < pv ? pv : key;
            key = km ? mx : mn;
        }
    }
    int m_final = 4095 - (int)(key & 0xFFFu);   // lane r (<32) = r-th best exact

    // publish exact-sorted indices for vectorized broadcast gather
    if (lane < KMAX) scand[w][lane] = m_final;

    // fused BN stats gather: lane = o
    const __half* ub = u + (size_t)b * N * O;
    size_t rowb = (size_t)b * N + n;
    float vv = __half2float(v[rowb * O + lane]);
    float gmax = -FLT_MAX, gmin = FLT_MAX, gs = 0.f, gs2 = 0.f;
    if (k == 20) {
        const int4* ip = (const int4*)&scand[w][0];
        int4 q0 = ip[0], q1 = ip[1], q2 = ip[2], q3 = ip[3], q4 = ip[4];
        float g[20];
        g[0]  = __half2float(ub[(size_t)q0.x * O + lane]);
        g[1]  = __half2float(ub[(size_t)q0.y * O + lane]);
        g[2]  = __half2float(ub[(size_t)q0.z * O + lane]);
        g[3]  = __half2float(ub[(size_t)q0.w * O + lane]);
        g[4]  = __half2float(ub[(size_t)q1.x * O + lane]);
        g[5]  = __half2float(ub[(size_t)q1.y * O + lane]);
        g[6]  = __half2float(ub[(size_t)q1.z * O + lane]);
        g[7]  = __half2float(ub[(size_t)q1.w * O + lane]);
        g[8]  = __half2float(ub[(size_t)q2.x * O + lane]);
        g[9]  = __half2float(ub[(size_t)q2.y * O + lane]);
        g[10] = __half2float(ub[(size_t)q2.z * O + lane]);
        g[11] = __half2float(ub[(size_t)q2.w * O + lane]);
        g[12] = __half2float(ub[(size_t)q3.x * O + lane]);
        g[13] = __half2float(ub[(size_t)q3.y * O + lane]);
        g[14] = __half2float(ub[(size_t)q3.z * O + lane]);
        g[15] = __half2float(ub[(size_t)q3.w * O + lane]);
        g[16] = __half2float(ub[(size_t)q4.x * O + lane]);
        g[17] = __half2float(ub[(size_t)q4.y * O + lane]);
        g[18] = __half2float(ub[(size_t)q4.z * O + lane]);
        g[19] = __half2float(ub[(size_t)q4.w * O + lane]);
#pragma unroll
        for (int kk = 0; kk < 20; ++kk) {
            gs += g[kk]; gs2 += g[kk] * g[kk];
            gmax = fmaxf(gmax, g[kk]); gmin = fminf(gmin, g[kk]);
        }
    } else {
        int mks[KMAX];
#pragma unroll
        for (int kk = 0; kk < KMAX; ++kk) mks[kk] = __shfl(m_final, kk);
        float g[KMAX];
#pragma unroll
        for (int kk = 0; kk < KMAX; ++kk)
            g[kk] = __half2float(ub[(size_t)mks[kk] * O + lane]);
#pragma unroll
        for (int kk = 0; kk < KMAX; ++kk) {
            if (kk < k) {
                gs += g[kk]; gs2 += g[kk] * g[kk];
                gmax = fmaxf(gmax, g[kk]); gmin = fminf(gmin, g[kk]);
            }
        }
    }
    float fk = (float)k;
    float s  = gs + fk * vv;
    float s2 = gs2 + 2.f * vv * gs + fk * vv * vv;
    ext[rowb * O + lane] = __halves2half2(__float2half(gmax + vv), __float2half(gmin + vv));
    rsum[t] = s; rsum2[t] = s2;
    __syncthreads();
    if (t < 64) {
        float a  = rsum[t] + rsum[t + 64] + rsum[t + 128] + rsum[t + 192];
        float a2 = rsum2[t] + rsum2[t + 64] + rsum2[t + 128] + rsum2[t + 192];
        float* sr = statsR + (size_t)(blockIdx.x & (NREP - 1)) * 128;
        atomicAdd(&sr[t], a);
        atomicAdd(&sr[64 + t], a2);
    }
}

// ---------- output: replica-reduce BN affine + pick extreme + leaky + transpose ----------
__global__ __launch_bounds__(256) void ec_out(const __half2* __restrict__ ext,
                                              const float* __restrict__ statsR,
                                              const float* __restrict__ gamma,
                                              const float* __restrict__ beta,
                                              const int* __restrict__ kptr,
                                              float* __restrict__ out) {
    __shared__ float res[64][65];
    __shared__ float scs[64], shs[64];
    const int blk = blockIdx.x;            // B*N/64
    const int b = blk >> 6;
    const int n0 = (blk & 63) << 6;
    const int t = threadIdx.x;
    if (t < 64) {
        float s = 0.f, s2 = 0.f;
#pragma unroll 8
        for (int r = 0; r < NREP; ++r) {
            s  += statsR[r * 128 + t];
            s2 += statsR[r * 128 + 64 + t];
        }
        int k = *kptr;
        float M = (float)B * (float)N * (float)k;
        float mean = s / M;
        float var = fmaxf(s2 / M - mean * mean, 0.f);
        float sc = gamma[t] * rsqrtf(var + 1e-5f);
        scs[t] = sc;
        shs[t] = beta[t] - mean * sc;
    }
    __syncthreads();
    {
        const int o = t & 63, ni = t >> 6;
        float sc = scs[o], sh = shs[o];
#pragma unroll 1
        for (int p = 0; p < 16; ++p) {
            int nl = ni * 16 + p;
            size_t a = ((size_t)b * N + n0 + nl) * O + o;
            __half2 e = ext[a];
            float y = (sc >= 0.f) ? __low2float(e) : __high2float(e);
            float z = sc * y + sh;
            res[nl][o] = (z >= 0.f) ? z : 0.2f * z;
        }
    }
    __syncthreads();
    {
        const int j = t & 63, oi = t >> 6;
#pragma unroll 1
        for (int p = 0; p < 16; ++p) {
            int o2 = oi * 16 + p;
            out[(size_t)b * O * N + (size_t)o2 * N + n0 + j] = res[j][o2];
        }
    }
}

extern "C" void kernel_launch(void* const* d_in, const int* in_sizes, int n_in,
                              void* d_out, int out_size, void* d_ws, size_t ws_size,
                              hipStream_t stream) {
    const float* x     = (const float*)d_in[0];
    const float* W     = (const float*)d_in[1];
    const float* gamma = (const float*)d_in[2];
    const float* beta  = (const float*)d_in[3];
    const int*   kptr  = (const int*)d_in[4];
    float* out = (float*)d_out;

    char* ws = (char*)d_ws;
    u32*    cand = (u32*)ws;    ws += (size_t)B * N * 32 * 8 * 4;  // 32 MB
    float*  xx   = (float*)ws;  ws += (size_t)B * N * 4;
    float*  xt   = (float*)ws;  ws += (size_t)B * N * C * 4;       // 8 MB
    u16*    xtb  = (u16*)ws;    ws += (size_t)B * N * C * 2;       // 4 MB
    __half* u_t  = (__half*)ws; ws += (size_t)B * N * O * 2;       // 4 MB
    __half* v_t  = (__half*)ws; ws += (size_t)B * N * O * 2;       // 4 MB
    __half2* ext = (__half2*)ws; ws += (size_t)B * N * O * 4;      // 8 MB
    float* statsR = (float*)ws; ws += (size_t)NREP * 128 * 4;      // 32 KB
    (void)ws;

    hipMemsetAsync(statsR, 0, NREP * 128 * 4, stream);
    ec_prep<<<B * N / 32, 256, 0, stream>>>(x, W, xx, xt, xtb, u_t, v_t);
    ec_gemm<<<dim3(N / 128, N / 128, B), 256, 0, stream>>>(xtb, xx, cand);
    ec_sel<<<dim3(N / 4, B), 256, 0, stream>>>(cand, xt, xx, u_t, v_t, kptr, ext, statsR);
    ec_out<<<B * N / 64, 256, 0, stream>>>(ext, statsR, gamma, beta, kptr, out);
}